// Round 1
// baseline (431.541 us; speedup 1.0000x reference)
//
#include <hip/hip_runtime.h>
#include <stdint.h>

#define BATCH 4
#define SEQ   2048
#define CH    1024
#define NH    16
#define HD    64

typedef __attribute__((ext_vector_type(8))) short bf16x8;
typedef __attribute__((ext_vector_type(4))) float f32x4;

__device__ inline unsigned short f2bf(float f) {
    unsigned u = __float_as_uint(f);
    u += 0x7fff + ((u >> 16) & 1);   // RNE
    return (unsigned short)(u >> 16);
}

__device__ inline void gld_lds16(const void* g, void* l) {
    __builtin_amdgcn_global_load_lds((const __attribute__((address_space(1))) void*)g,
                                     (__attribute__((address_space(3))) void*)l,
                                     16, 0, 0);
}

// ---------------- fp32 -> bf16 convert (vectorized) ----------------
__global__ __launch_bounds__(256) void cvt_bf16_k(const float* __restrict__ in,
                                                  unsigned short* __restrict__ out, int n) {
    int i = (blockIdx.x * 256 + threadIdx.x) * 8;
    if (i >= n) return;
    f32x4 a = *(const f32x4*)(in + i);
    f32x4 b = *(const f32x4*)(in + i + 4);
    union { bf16x8 v; unsigned short s[8]; } o;
    o.s[0] = f2bf(a[0]); o.s[1] = f2bf(a[1]); o.s[2] = f2bf(a[2]); o.s[3] = f2bf(a[3]);
    o.s[4] = f2bf(b[0]); o.s[5] = f2bf(b[1]); o.s[6] = f2bf(b[2]); o.s[7] = f2bf(b[3]);
    *(bf16x8*)(out + i) = o.v;
}

// ---------------- W (K x N fp32) -> W^T (N x K bf16) ----------------
__global__ __launch_bounds__(256) void transpose_w_k(const float* __restrict__ W,
                                                     unsigned short* __restrict__ Wt) {
    __shared__ float tile[32][33];
    const int bx = blockIdx.x * 32;   // n block
    const int by = blockIdx.y * 32;   // k block
    const int tx = threadIdx.x & 31;
    const int ty = threadIdx.x >> 5;  // 0..7
#pragma unroll
    for (int i = 0; i < 32; i += 8)
        tile[ty + i][tx] = W[(size_t)(by + ty + i) * CH + bx + tx];
    __syncthreads();
#pragma unroll
    for (int i = 0; i < 32; i += 8)
        Wt[(size_t)(bx + ty + i) * CH + by + tx] = f2bf(tile[tx][ty + i]);
}

// ---------------- GEMM: A(MxK bf16) @ Bt(NxK bf16)^T + bias ----------------
// MODE 0: out bf16, layout (B,H,T,64)   [Q/K projections]
// MODE 1: out bf16, layout (B,H,64,T)   [V projection, transposed]
// MODE 2: out fp32, row-major MxN       [final output projection]
template <int MODE>
__global__ __launch_bounds__(256, 2)
void gemm_bt(const unsigned short* __restrict__ A,
             const unsigned short* __restrict__ Bt,
             const float* __restrict__ bias,
             void* __restrict__ outp,
             int M, int N, int K) {
    __shared__ unsigned short As[128 * 64];
    __shared__ unsigned short Bs[128 * 64];
    const int tid  = threadIdx.x;
    const int lane = tid & 63;
    const int w    = tid >> 6;
    const int nbn  = N >> 7;
    const int m0   = (blockIdx.x / nbn) << 7;
    const int n0   = (blockIdx.x % nbn) << 7;
    const int wrow = (w >> 1) << 6;
    const int wcol = (w & 1) << 6;
    const int lr   = lane & 15;
    const int lg   = lane >> 4;

    f32x4 acc[4][4] = {};

    for (int k0 = 0; k0 < K; k0 += 64) {
#pragma unroll
        for (int i = 0; i < 4; ++i) {
            int chunk = i * 256 + tid;
            int row = chunk >> 3;
            int c8  = (chunk & 7) << 3;
            gld_lds16(A  + (size_t)(m0 + row) * K + k0 + c8, (char*)As + chunk * 16);
            gld_lds16(Bt + (size_t)(n0 + row) * K + k0 + c8, (char*)Bs + chunk * 16);
        }
        __syncthreads();
#pragma unroll
        for (int kk = 0; kk < 2; ++kk) {
            bf16x8 af[4], bfr[4];
#pragma unroll
            for (int f = 0; f < 4; ++f)
                af[f] = *(const bf16x8*)(As + (wrow + f * 16 + lr) * 64 + kk * 32 + lg * 8);
#pragma unroll
            for (int f = 0; f < 4; ++f)
                bfr[f] = *(const bf16x8*)(Bs + (wcol + f * 16 + lr) * 64 + kk * 32 + lg * 8);
#pragma unroll
            for (int i = 0; i < 4; ++i)
#pragma unroll
                for (int j = 0; j < 4; ++j)
                    acc[i][j] = __builtin_amdgcn_mfma_f32_16x16x32_bf16(af[i], bfr[j], acc[i][j], 0, 0, 0);
        }
        __syncthreads();
    }

    float bvals[4];
#pragma unroll
    for (int j = 0; j < 4; ++j) bvals[j] = bias[n0 + wcol + j * 16 + lr];

#pragma unroll
    for (int i = 0; i < 4; ++i) {
        const int mbase = m0 + wrow + i * 16 + lg * 4;
#pragma unroll
        for (int j = 0; j < 4; ++j) {
            const int n = n0 + wcol + j * 16 + lr;
            if (MODE == 2) {
                float* out = (float*)outp;
#pragma unroll
                for (int r = 0; r < 4; ++r)
                    out[(size_t)(mbase + r) * N + n] = acc[i][j][r] + bvals[j];
            } else if (MODE == 0) {
                unsigned short* out = (unsigned short*)outp;
                const int h = n >> 6, d = n & 63;
#pragma unroll
                for (int r = 0; r < 4; ++r) {
                    const int m = mbase + r;
                    const int b = m >> 11, t = m & 2047;
                    out[((size_t)(b * NH + h) * SEQ + t) * HD + d] = f2bf(acc[i][j][r] + bvals[j]);
                }
            } else { // MODE 1: (B,H,D,T), pack 4 consecutive t
                unsigned short* out = (unsigned short*)outp;
                const int h = n >> 6, d = n & 63;
                const int b = mbase >> 11, t = mbase & 2047;
                union { unsigned short s[4]; uint2 v; } pk;
#pragma unroll
                for (int r = 0; r < 4; ++r) pk.s[r] = f2bf(acc[i][j][r] + bvals[j]);
                *(uint2*)(out + ((size_t)(b * NH + h) * HD + d) * SEQ + t) = pk.v;
            }
        }
    }
}

// ---------------- flash attention: per (bh, 64-row q tile) ----------------
__global__ __launch_bounds__(256, 4)
void attn_k(const unsigned short* __restrict__ Qh,   // (BH, T, 64)
            const unsigned short* __restrict__ Kh,   // (BH, T, 64)
            const unsigned short* __restrict__ Vt,   // (BH, 64, T)
            unsigned short* __restrict__ O) {        // (B, T, H*64)
    __shared__ unsigned short Ks[64 * 64];
    __shared__ unsigned short Vs[64 * 64];          // [d][kv]
    __shared__ unsigned short Ps[4][16][64];
    const int qt = blockIdx.x;
    const int bh = blockIdx.y;
    const int q0 = qt << 6;
    const int tid  = threadIdx.x;
    const int lane = tid & 63;
    const int w    = tid >> 6;
    const int lr   = lane & 15;
    const int lg   = lane >> 4;

    bf16x8 qf[2];
    {
        const unsigned short* qb = Qh + ((size_t)bh * SEQ + q0 + w * 16 + lr) * HD;
        qf[0] = *(const bf16x8*)(qb + lg * 8);
        qf[1] = *(const bf16x8*)(qb + 32 + lg * 8);
    }

    float mrun[4], lrun[4];
    f32x4 oacc[4] = {};
#pragma unroll
    for (int r = 0; r < 4; ++r) { mrun[r] = -3e38f; lrun[r] = 0.f; }

    for (int kt = 0; kt <= qt; ++kt) {
        const int kv0 = kt << 6;
#pragma unroll
        for (int i = 0; i < 2; ++i) {
            int chunk = i * 256 + tid;
            int row = chunk >> 3;
            int c8  = (chunk & 7) << 3;
            gld_lds16(Kh + ((size_t)bh * SEQ + kv0 + row) * HD + c8, (char*)Ks + chunk * 16);
            gld_lds16(Vt + ((size_t)bh * HD + row) * SEQ + kv0 + c8, (char*)Vs + chunk * 16);
        }
        __syncthreads();

        f32x4 s[4] = {};
#pragma unroll
        for (int f = 0; f < 4; ++f)
#pragma unroll
            for (int kk = 0; kk < 2; ++kk) {
                bf16x8 kb = *(const bf16x8*)(Ks + (f * 16 + lr) * 64 + kk * 32 + lg * 8);
                s[f] = __builtin_amdgcn_mfma_f32_16x16x32_bf16(qf[kk], kb, s[f], 0, 0, 0);
            }

        float rmax[4];
#pragma unroll
        for (int r = 0; r < 4; ++r) rmax[r] = -3e38f;
        const bool diag = (kt == qt);
#pragma unroll
        for (int f = 0; f < 4; ++f)
#pragma unroll
            for (int r = 0; r < 4; ++r) {
                float v = s[f][r] * 0.125f;
                if (diag && (kv0 + f * 16 + lr > q0 + w * 16 + lg * 4 + r)) v = -3e38f;
                s[f][r] = v;
                rmax[r] = fmaxf(rmax[r], v);
            }
#pragma unroll
        for (int d = 1; d < 16; d <<= 1)
#pragma unroll
            for (int r = 0; r < 4; ++r) rmax[r] = fmaxf(rmax[r], __shfl_xor(rmax[r], d));

        float corr[4], psum[4];
#pragma unroll
        for (int r = 0; r < 4; ++r) {
            float mn = fmaxf(mrun[r], rmax[r]);
            corr[r] = __expf(mrun[r] - mn);
            mrun[r] = mn;
            psum[r] = 0.f;
        }
#pragma unroll
        for (int f = 0; f < 4; ++f)
#pragma unroll
            for (int r = 0; r < 4; ++r) {
                float pv = __expf(s[f][r] - mrun[r]);
                s[f][r] = pv;
                psum[r] += pv;
            }
#pragma unroll
        for (int d = 1; d < 16; d <<= 1)
#pragma unroll
            for (int r = 0; r < 4; ++r) psum[r] += __shfl_xor(psum[r], d);
#pragma unroll
        for (int r = 0; r < 4; ++r) lrun[r] = lrun[r] * corr[r] + psum[r];
#pragma unroll
        for (int f = 0; f < 4; ++f)
#pragma unroll
            for (int r = 0; r < 4; ++r) oacc[f][r] *= corr[r];

#pragma unroll
        for (int f = 0; f < 4; ++f)
#pragma unroll
            for (int r = 0; r < 4; ++r)
                Ps[w][lg * 4 + r][f * 16 + lr] = f2bf(s[f][r]);
        __syncthreads();

        bf16x8 pa[2];
        pa[0] = *(const bf16x8*)(&Ps[w][lr][lg * 8]);
        pa[1] = *(const bf16x8*)(&Ps[w][lr][32 + lg * 8]);
#pragma unroll
        for (int f = 0; f < 4; ++f)
#pragma unroll
            for (int kk = 0; kk < 2; ++kk) {
                bf16x8 vb = *(const bf16x8*)(Vs + (f * 16 + lr) * 64 + kk * 32 + lg * 8);
                oacc[f] = __builtin_amdgcn_mfma_f32_16x16x32_bf16(pa[kk], vb, oacc[f], 0, 0, 0);
            }
        __syncthreads();
    }

    const int b = bh >> 4, h = bh & 15;
    float inv[4];
#pragma unroll
    for (int r = 0; r < 4; ++r) inv[r] = 1.0f / lrun[r];
#pragma unroll
    for (int f = 0; f < 4; ++f) {
        const int d = f * 16 + lr;
#pragma unroll
        for (int r = 0; r < 4; ++r) {
            const int t = q0 + w * 16 + lg * 4 + r;
            O[((size_t)b * SEQ + t) * CH + h * HD + d] = f2bf(oacc[f][r] * inv[r]);
        }
    }
}

extern "C" void kernel_launch(void* const* d_in, const int* in_sizes, int n_in,
                              void* d_out, int out_size, void* d_ws, size_t ws_size,
                              hipStream_t stream) {
    const float* Q  = (const float*)d_in[0];
    const float* K  = (const float*)d_in[1];
    const float* V  = (const float*)d_in[2];
    // d_in[3] = mask: always causal triu(k=1); applied analytically in attn_k
    const float* Wq = (const float*)d_in[4];
    const float* bq = (const float*)d_in[5];
    const float* Wk = (const float*)d_in[6];
    const float* bk = (const float*)d_in[7];
    const float* Wv = (const float*)d_in[8];
    const float* bv = (const float*)d_in[9];
    const float* Wo = (const float*)d_in[10];
    const float* bo = (const float*)d_in[11];
    float* out = (float*)d_out;

    const size_t SZ_ACT = (size_t)BATCH * SEQ * CH;  // 8388608
    const size_t SZ_W   = (size_t)CH * CH;           // 1048576

    char* p = (char*)d_ws;
    unsigned short* Qbf = (unsigned short*)p; p += SZ_ACT * 2;
    unsigned short* Kbf = (unsigned short*)p; p += SZ_ACT * 2;
    unsigned short* Vbf = (unsigned short*)p; p += SZ_ACT * 2;
    unsigned short* WqT = (unsigned short*)p; p += SZ_W * 2;
    unsigned short* WkT = (unsigned short*)p; p += SZ_W * 2;
    unsigned short* WvT = (unsigned short*)p; p += SZ_W * 2;
    unsigned short* WoT = (unsigned short*)p; p += SZ_W * 2;
    unsigned short* Qhb = (unsigned short*)p; p += SZ_ACT * 2;
    unsigned short* Khb = (unsigned short*)p; p += SZ_ACT * 2;
    unsigned short* Vtb = (unsigned short*)p; p += SZ_ACT * 2;
    unsigned short* Ob  = Qbf;  // Qbf is dead after the Q projection; reuse for attn output

    const int nconv = (int)SZ_ACT;
    const int cblocks = (int)(SZ_ACT / (256 * 8));
    cvt_bf16_k<<<cblocks, 256, 0, stream>>>(Q, Qbf, nconv);
    cvt_bf16_k<<<cblocks, 256, 0, stream>>>(K, Kbf, nconv);
    cvt_bf16_k<<<cblocks, 256, 0, stream>>>(V, Vbf, nconv);

    transpose_w_k<<<dim3(32, 32), 256, 0, stream>>>(Wq, WqT);
    transpose_w_k<<<dim3(32, 32), 256, 0, stream>>>(Wk, WkT);
    transpose_w_k<<<dim3(32, 32), 256, 0, stream>>>(Wv, WvT);
    transpose_w_k<<<dim3(32, 32), 256, 0, stream>>>(Wo, WoT);

    const int M = BATCH * SEQ;  // 8192
    gemm_bt<0><<<(M / 128) * (CH / 128), 256, 0, stream>>>(Qbf, WqT, bq, Qhb, M, CH, CH);
    gemm_bt<0><<<(M / 128) * (CH / 128), 256, 0, stream>>>(Kbf, WkT, bk, Khb, M, CH, CH);
    gemm_bt<1><<<(M / 128) * (CH / 128), 256, 0, stream>>>(Vbf, WvT, bv, Vtb, M, CH, CH);

    attn_k<<<dim3(SEQ / 64, BATCH * NH), 256, 0, stream>>>(Qhb, Khb, Vtb, Ob);

    gemm_bt<2><<<(M / 128) * (CH / 128), 256, 0, stream>>>(Ob, WoT, bo, out, M, CH, CH);
}